// Round 8
// baseline (604.948 us; speedup 1.0000x reference)
//
#include <hip/hip_runtime.h>

#define B_TOT 16384
#define T_STEPS 128
#define F_IN 29
#define K_HID 512
#define NW 4        // waves per block (node dimension split 4 ways)
#define NTILE 8     // node tiles per wave = 512 / (16*NW)

typedef __attribute__((ext_vector_type(8))) short short8;   // 8 bf16 (MFMA A/B frag)
typedef __attribute__((ext_vector_type(4))) float floatx4;  // MFMA C/D frag
typedef __attribute__((ext_vector_type(2))) float f32x2;    // packed f32 (v_pk_*)

__device__ __forceinline__ short bf16_hi_bits(float x) {
    return (short)(__float_as_uint(x) >> 16);
}
__device__ __forceinline__ float bf16_hi_f(float x) {
    return __uint_as_float(__float_as_uint(x) & 0xffff0000u);
}

// tanh pair, trans-minimized: 3 trans/pair (2 exp + 1 shared rcp).
// exp(2x) = exp2(x * 2log2e); 1/d0 = d1*rcp(d0*d1), 1/d1 = d0*rcp(d0*d1).
__device__ __forceinline__ f32x2 tanh2(f32x2 x) {
    f32x2 a = x * 2.88539008177793f;    // 2*log2(e)
    f32x2 e;
    e.x = __builtin_amdgcn_exp2f(a.x);
    e.y = __builtin_amdgcn_exp2f(a.y);
    f32x2 d = e + 1.0f;
    float rp = __builtin_amdgcn_rcpf(d.x * d.y);
    f32x2 r = {d.y * rp, d.x * rp};
    return 1.0f - 2.0f * r;
}

// sum over each 16-lane row via DPP row_shr prefix (VALU-only, no DS);
// result valid at lane 15 of each row.
__device__ __forceinline__ float dpp_sum16(float v) {
    int t;
    t = __builtin_amdgcn_update_dpp(0, __float_as_int(v), 0x111, 0xF, 0xF, true);
    v += __int_as_float(t);
    t = __builtin_amdgcn_update_dpp(0, __float_as_int(v), 0x112, 0xF, 0xF, true);
    v += __int_as_float(t);
    t = __builtin_amdgcn_update_dpp(0, __float_as_int(v), 0x114, 0xF, 0xF, true);
    v += __int_as_float(t);
    t = __builtin_amdgcn_update_dpp(0, __float_as_int(v), 0x118, 0xF, 0xF, true);
    v += __int_as_float(t);
    return v;
}

// v6 with the LDS footprint collapsed 37.4KB -> 4.6KB (the R2..R6 rounds all
// showed ~27% occupancy = ~2.2 blocks/CU, LDS-capped; R1 showed 46% at small
// LDS). wlo moves back to VGPRs (+32 regs, ~104-115 total: still the <=128
// bracket = 4 waves/SIMD), so residency returns to grid-limited 4 blocks/CU
// = 16 waves/CU and the ~125us of un-hidden latency gets covered by TLP.
// Numerics byte-identical to v6/v5/v2 (absmax 0.0078125).
__global__ __launch_bounds__(256, 2)
void narx_v7(const float* __restrict__ X,   // [B][T][29]
             const float* __restrict__ y0,  // [B][3]
             const float* __restrict__ W1,  // [32][512]
             const float* __restrict__ b1,  // [512]
             const float* __restrict__ W2,  // [512]
             const float* __restrict__ b2,  // [1]
             float* __restrict__ out)       // [B][T]
{
    // sA[buf][0]=hi, sA[buf][1]=lo; element (row m, k) at [m*32+k]
    __shared__ __align__(16) short sA[2][2][16 * 32];   // 4096 B
    __shared__ __align__(16) float pp[2][16][NW];       // 512 B, [row][wave]

    const int tid  = threadIdx.x;       // 0..255
    const int wv   = tid >> 6;          // wave id 0..3
    const int lane = tid & 63;
    const int q    = lane >> 4;         // 0..3
    const int m    = lane & 15;         // batch row (A/C) and node col (B)
    const size_t row0 = (size_t)blockIdx.x * 16;

    // ---- one-time: this wave's W1 B-frags (hi AND lo in regs), b1, W2 ----
    short8 whi[NTILE], wlo[NTILE];
    float b1v[NTILE], w2v[NTILE];
    #pragma unroll
    for (int nt = 0; nt < NTILE; ++nt) {
        int node = wv * (NTILE * 16) + nt * 16 + m;
        #pragma unroll
        for (int j = 0; j < 8; ++j) {
            int k = q * 8 + j;
            float v  = W1[k * K_HID + node];
            float hf = bf16_hi_f(v);
            whi[nt][j] = bf16_hi_bits(v);
            wlo[nt][j] = bf16_hi_bits(v - hf);
        }
        b1v[nt] = b1[node];
        w2v[nt] = W2[node];
    }
    const float b2v = b2[0];

    // per-lane feedback for row m (replicated over q and wv), v2-identical
    float fb0 = y0[(row0 + m) * 3 + 0];
    float fb1 = y0[(row0 + m) * 3 + 1];
    float fb2 = y0[(row0 + m) * 3 + 2];

    // ---- X staging: 464 elems/step over 256 threads (<=2 each) ----
    const float* Xblk = X + row0 * (T_STEPS * F_IN);
    const int f0 = tid, f1 = tid + 256;
    const bool v1 = (f1 < 16 * F_IN);
    const int r0 = f0 / F_IN, c0 = f0 - r0 * F_IN;
    const int r1 = f1 / F_IN, c1 = f1 - r1 * F_IN;
    const int xo0 = r0 * (T_STEPS * F_IN) + c0;
    const int xo1 = r1 * (T_STEPS * F_IN) + c1;
    const int a0i = r0 * 32 + c0;
    const int a1i = r1 * 32 + c1;

    // stage X(0): convert to hi/lo at stage time
    {
        float a0 = Xblk[xo0];
        float a1 = v1 ? Xblk[xo1] : 0.f;
        float h0 = bf16_hi_f(a0), h1 = bf16_hi_f(a1);
        sA[0][0][a0i] = bf16_hi_bits(a0);
        sA[0][1][a0i] = bf16_hi_bits(a0 - h0);
        if (v1) {
            sA[0][0][a1i] = bf16_hi_bits(a1);
            sA[0][1][a1i] = bf16_hi_bits(a1 - h1);
        }
    }

    float4 pv = make_float4(0.f, 0.f, 0.f, 0.f);

    for (int t = 0; t < T_STEPS; ++t) {
        const int cur = t & 1;
        __syncthreads();   // publishes pp(t-1), sA[cur]=X(t)
                           // (t=0: also covers sA[0] prologue writes)

        // issue global prefetch of X(t+1) (converted+written at step end)
        const int tn = (t + 1 < T_STEPS) ? (t + 1) : t;
        float xp0 = Xblk[xo0 + tn * F_IN];
        float xp1 = v1 ? Xblk[xo1 + tn * F_IN] : 0.f;

        // ---- combine pred(t-1); shift feedback; output ----
        if (t > 0) {
            const int pb = cur ^ 1;
            float4 s = *(const float4*)&pp[pb][m][0];
            float fbn = (s.x + s.y) + (s.z + s.w) + b2v;
            fb2 = fb1; fb1 = fb0; fb0 = fbn;
            if (wv == 0 && m < 4) {        // lane (q, m<4) owns row q*4+m
                const int ro = q * 4 + m;
                float4 so = *(const float4*)&pp[pb][ro][0];
                float po = (so.x + so.y) + (so.z + so.w) + b2v;
                pv = make_float4(pv.y, pv.z, pv.w, po);
                if (((t - 1) & 3) == 3)
                    *(float4*)&out[(row0 + ro) * T_STEPS + (t - 4)] = pv;
            }
        }

        // ---- A-frag: 2x ds_read_b128 + fb patch on q==3 lanes ----
        short8 ahi = *(const short8*)&sA[cur][0][m * 32 + q * 8];
        short8 alo = *(const short8*)&sA[cur][1][m * 32 + q * 8];
        if (q == 3) {   // k = 29,30,31 <- fb0,fb1,fb2 (lane-local, row m)
            float h;
            h = bf16_hi_f(fb0); ahi[5] = bf16_hi_bits(fb0); alo[5] = bf16_hi_bits(fb0 - h);
            h = bf16_hi_f(fb1); ahi[6] = bf16_hi_bits(fb1); alo[6] = bf16_hi_bits(fb1 - h);
            h = bf16_hi_f(fb2); ahi[7] = bf16_hi_bits(fb2); alo[7] = bf16_hi_bits(fb2 - h);
        }

        // ---- 8 node tiles: bf16x3 MFMA + packed tanh + W2 partial ----
        f32x2 pa01 = {0.f, 0.f}, pa23 = {0.f, 0.f};
        #pragma unroll
        for (int nt = 0; nt < NTILE; ++nt) {
            const float bb = b1v[nt];
            floatx4 c = {bb, bb, bb, bb};
            c = __builtin_amdgcn_mfma_f32_16x16x32_bf16(ahi, whi[nt], c, 0, 0, 0);
            c = __builtin_amdgcn_mfma_f32_16x16x32_bf16(ahi, wlo[nt], c, 0, 0, 0);
            c = __builtin_amdgcn_mfma_f32_16x16x32_bf16(alo, whi[nt], c, 0, 0, 0);
            // C/D: col(node) = lane&15, row(batch) = q*4 + reg
            f32x2 t01 = tanh2((f32x2){c[0], c[1]});
            f32x2 t23 = tanh2((f32x2){c[2], c[3]});
            pa01 += t01 * w2v[nt];
            pa23 += t23 * w2v[nt];
        }

        // ---- reduce over the 16 node cols: DPP prefix, sum lands at m==15 ----
        pa01.x = dpp_sum16(pa01.x);
        pa01.y = dpp_sum16(pa01.y);
        pa23.x = dpp_sum16(pa23.x);
        pa23.y = dpp_sum16(pa23.y);
        if (m == 15) {   // rows q*4+0..3, one slot per wave
            pp[cur][q * 4 + 0][wv] = pa01.x;
            pp[cur][q * 4 + 1][wv] = pa01.y;
            pp[cur][q * 4 + 2][wv] = pa23.x;
            pp[cur][q * 4 + 3][wv] = pa23.y;
        }

        // ---- stage X(t+1): convert hi/lo, write into the other buffer ----
        {
            float h0 = bf16_hi_f(xp0), h1 = bf16_hi_f(xp1);
            sA[cur ^ 1][0][a0i] = bf16_hi_bits(xp0);
            sA[cur ^ 1][1][a0i] = bf16_hi_bits(xp0 - h0);
            if (v1) {
                sA[cur ^ 1][0][a1i] = bf16_hi_bits(xp1);
                sA[cur ^ 1][1][a1i] = bf16_hi_bits(xp1 - h1);
            }
        }
    }

    // ---- tail: combine pred(127), flush last output quad ----
    __syncthreads();
    if (wv == 0 && m < 4) {
        const int pb = (T_STEPS - 1) & 1;
        const int ro = q * 4 + m;
        float4 so = *(const float4*)&pp[pb][ro][0];
        float po = (so.x + so.y) + (so.z + so.w) + b2v;
        pv = make_float4(pv.y, pv.z, pv.w, po);
        *(float4*)&out[(row0 + ro) * T_STEPS + (T_STEPS - 4)] = pv;
    }
}

extern "C" void kernel_launch(void* const* d_in, const int* in_sizes, int n_in,
                              void* d_out, int out_size, void* d_ws, size_t ws_size,
                              hipStream_t stream) {
    const float* X  = (const float*)d_in[0];
    const float* y0 = (const float*)d_in[1];
    const float* W1 = (const float*)d_in[2];
    const float* b1 = (const float*)d_in[3];
    const float* W2 = (const float*)d_in[4];
    const float* b2 = (const float*)d_in[5];
    float* out = (float*)d_out;

    dim3 grid(B_TOT / 16);   // 1024 blocks x 4 waves; 4 blocks/CU grid-limited
    dim3 block(64 * NW);
    narx_v7<<<grid, block, 0, stream>>>(X, y0, W1, b1, W2, b2, out);
}